// Round 15
// baseline (11914.062 us; speedup 1.0000x reference)
//
#include <hip/hip_runtime.h>
#include <hip/hip_bf16.h>

typedef __attribute__((ext_vector_type(2))) _Float16 half2v;
typedef __attribute__((ext_vector_type(4))) _Float16 half4;
typedef __attribute__((ext_vector_type(8))) _Float16 half8;
typedef __attribute__((ext_vector_type(4))) float f32x4;
typedef __attribute__((ext_vector_type(2))) float f32x2;

#define T_ 512
#define B_ 256
#define I_ 64
#define H_ 512
#define BH (B_ * H_)
#define NKS0 36
#define NKS1 64

// Wp[((cb*4+w)*NKS+ks)*256 + l*4 + i] = W[g = w*512 + cb*16 + (l&15)][k = ks*16 + (l>>4)*4 + i]
template<int NKS, int K0>
__global__ void pack_w(const float* __restrict__ Wih, const float* __restrict__ Whh,
                       _Float16* __restrict__ Wp) {
    int idx = blockIdx.x * 256 + threadIdx.x;
    int i  = idx & 3;
    int l  = (idx >> 2) & 63;
    int rest = idx >> 8;
    int ks = rest % NKS;
    int r  = rest / NKS;
    int w  = r & 3;
    int cb = r >> 2;
    int g  = w * H_ + cb * 16 + (l & 15);
    int k  = ks * 16 + ((l >> 4) << 2) + i;
    float v = (k < K0) ? Wih[(size_t)g * K0 + k] : Whh[(size_t)g * H_ + (k - K0)];
    Wp[idx] = (_Float16)v;
}

// ---- flags: ALWAYS MALL (sc0 sc1) — the only HW-validated progress path ----
__device__ __forceinline__ unsigned fload(const unsigned* p) {
    unsigned v;
    asm volatile("global_load_dword %0, %1, off sc0 sc1\n\ts_waitcnt vmcnt(0)"
                 : "=&v"(v) : "v"(p) : "memory");
    return v;
}
__device__ __forceinline__ void fstore(unsigned* p, unsigned v) {
    asm volatile("global_store_dword %0, %1, off sc0 sc1" :: "v"(p), "v"(v) : "memory");
}
template<bool FAST> __device__ __forceinline__ f32x4 gload16(const void* p) {
    f32x4 v;
    if (FAST) asm volatile("global_load_dwordx4 %0, %1, off sc0" : "=&v"(v) : "v"(p) : "memory");
    else      asm volatile("global_load_dwordx4 %0, %1, off sc0 sc1" : "=&v"(v) : "v"(p) : "memory");
    return v;
}
template<bool FAST> __device__ __forceinline__ void fstore16(void* p, f32x4 v) {
    if (FAST) asm volatile("global_store_dwordx4 %0, %1, off sc0" :: "v"(p), "v"(v) : "memory");
    else      asm volatile("global_store_dwordx4 %0, %1, off sc0 sc1" :: "v"(p), "v"(v) : "memory");
}

__device__ __forceinline__ float sigm(float z) { return 1.f / (1.f + __expf(-z)); }

#define CAT8(lo, hi) __builtin_shufflevector(lo, hi, 0, 1, 2, 3, 4, 5, 6, 7)
#define MFMA32(a, b, c) __builtin_amdgcn_mfma_f32_16x16x32_f16(a, b, c, 0, 0, 0)

// VAR 0: baseline (gate-per-wave both layers). VAR 1: layer1 K-split (wave q owns
// K-quarter for all 4 gates; A-loads amortized over 8 MFMAs; partial sums in LDS).
// VAR 2: baseline + one extra (satisfied) MALL poll per step = MALL RT probe.
template<bool FAST, int VAR>
__device__ __forceinline__ void run_lstm(
    int g, int cb, char* smem,
    const float* __restrict__ x,
    const _Float16* __restrict__ Wp0, const _Float16* __restrict__ Wp1,
    const float* __restrict__ bih0, const float* __restrict__ bhh0,
    const float* __restrict__ bih1, const float* __restrict__ bhh1,
    _Float16* __restrict__ h1buf, _Float16* __restrict__ h2buf,
    unsigned* __restrict__ bar)
{
    const int tid = threadIdx.x;
    const int w = tid >> 6, l = tid & 63;
    const int lr = l & 15, lk = l >> 4;
    const int R0 = g * 32, c0 = cb * 16;
    const int xsw = lr << 4;

    float* gA = (float*)(smem + 65536);              // [4][32][18] layer0 gates
    float* gB = (float*)(smem + 65536 + 9216);       // V0/V2: [4][32][18]; V1: [4][32][66]
    _Float16* hbuf = (_Float16*)(smem + 108544);     // [2][32][16]

    unsigned* grpflags = bar + (size_t)(g * 32) * 64;
    unsigned* myflag   = grpflags + (size_t)cb * 64;

    const int er = (tid >> 3) & 31;
    const int ec = (tid & 7) << 1;
    const bool lay1 = tid >= 256;

    float br[4][2];
    {
        const float* bi = lay1 ? bih1 : bih0;
        const float* bh = lay1 ? bhh1 : bhh0;
        #pragma unroll
        for (int q = 0; q < 4; ++q)
            #pragma unroll
            for (int cc = 0; cc < 2; ++cc) {
                int gc = q * H_ + c0 + ec + cc;
                br[q][cc] = bi[gc] + bh[gc];
            }
    }

    // resident weights as half8 K32-fragments (CAT8 done ONCE at init)
    half8 bregs[32];
    if (w < 4) {
        const _Float16* wb = Wp0 + ((size_t)(cb * 4 + w) * NKS0) * 256 + l * 4;
        #pragma unroll
        for (int t = 0; t < 18; ++t)
            bregs[t] = CAT8(*(const half4*)(wb + (2 * t) * 256),
                            *(const half4*)(wb + (2 * t + 1) * 256));
    } else if (VAR == 1) {
        int q = w - 4;
        #pragma unroll
        for (int nt = 0; nt < 4; ++nt) {
            const _Float16* wbn = Wp1 + ((size_t)(cb * 4 + nt) * NKS1) * 256 + l * 4;
            #pragma unroll
            for (int k2 = 0; k2 < 8; ++k2) {
                int ks = q * 16 + k2 * 2;
                bregs[nt * 8 + k2] = CAT8(*(const half4*)(wbn + ks * 256),
                                          *(const half4*)(wbn + (ks + 1) * 256));
            }
        }
    } else {
        const _Float16* wb = Wp1 + ((size_t)(cb * 4 + (w - 4)) * NKS1) * 256 + l * 4;
        #pragma unroll
        for (int t = 0; t < 32; ++t)
            bregs[t] = CAT8(*(const half4*)(wb + (2 * t) * 256),
                            *(const half4*)(wb + (2 * t + 1) * 256));
    }

    f32x2 cstr = {0.f, 0.f};

    for (int tt = 0; tt <= T_; ++tt) {
        f32x4 xr0[4], xr1[4];
        if (w < 4 && tt < T_) {
            const float* xa = x + (size_t)(R0 + lr) * (T_ * I_) + tt * I_ + lk * 4;
            const float* xb = x + (size_t)(R0 + 16 + lr) * (T_ * I_) + tt * I_ + lk * 4;
            #pragma unroll
            for (int ks = 0; ks < 4; ++ks) {
                xr0[ks] = *(const f32x4*)(xa + ks * 16);
                xr1[ks] = *(const f32x4*)(xb + ks * 16);
            }
        }

        // ---- poll ----
        if (tt > 0 && w == 0) {
            const unsigned tgt = (unsigned)tt;
            while (true) {
                unsigned v = fload(grpflags + (size_t)(l & 31) * 64);
                if (__all(v >= tgt)) break;
                __builtin_amdgcn_s_sleep(1);
            }
            if (VAR == 2) {   // MALL RT probe: one extra satisfied poll round trip
                unsigned vv = fload(grpflags + (size_t)(l & 31) * 64);
                asm volatile("" :: "v"(vv));
            }
        }
        __syncthreads();

        // ---- stage tile ----
        {
            const _Float16* h1p = h1buf + ((tt + 1) & 1) * BH;
            const _Float16* h2p = h2buf + (tt & 1) * BH;
            f32x4 t[8];
            #pragma unroll
            for (int it = 0; it < 8; ++it) {
                int cch = tid + it * 512;
                int row = cch >> 7, g16 = cch & 127;
                const _Float16* src = (g16 < 64)
                    ? h1p + (size_t)(R0 + row) * H_ + (g16 << 3)
                    : h2p + (size_t)(R0 + row) * H_ + ((g16 - 64) << 3);
                t[it] = gload16<FAST>(src);
            }
            asm volatile("s_waitcnt vmcnt(0)" ::: "memory");
            __builtin_amdgcn_sched_barrier(0);
            #pragma unroll
            for (int it = 0; it < 8; ++it) {
                int cch = tid + it * 512;
                int row = cch >> 7, g16 = cch & 127;
                *(f32x4*)(smem + row * 2048 + ((g16 ^ (row & 15)) << 4)) = t[it];
            }
        }
        __syncthreads();

        // ---- MFMA ----
        if (w < 4) {
            if (tt < T_) {
                f32x4 aE0={0,0,0,0}, aO0={0,0,0,0}, aE1={0,0,0,0}, aO1={0,0,0,0};
                #pragma unroll
                for (int t = 0; t < 2; ++t) {
                    half4 lo0 = {(_Float16)xr0[2*t][0], (_Float16)xr0[2*t][1], (_Float16)xr0[2*t][2], (_Float16)xr0[2*t][3]};
                    half4 hi0 = {(_Float16)xr0[2*t+1][0], (_Float16)xr0[2*t+1][1], (_Float16)xr0[2*t+1][2], (_Float16)xr0[2*t+1][3]};
                    half4 lo1 = {(_Float16)xr1[2*t][0], (_Float16)xr1[2*t][1], (_Float16)xr1[2*t][2], (_Float16)xr1[2*t][3]};
                    half4 hi1 = {(_Float16)xr1[2*t+1][0], (_Float16)xr1[2*t+1][1], (_Float16)xr1[2*t+1][2], (_Float16)xr1[2*t+1][3]};
                    half8 a0 = CAT8(lo0, hi0), a1 = CAT8(lo1, hi1);
                    if (t & 1) { aO0 = MFMA32(a0, bregs[t], aO0); aO1 = MFMA32(a1, bregs[t], aO1); }
                    else       { aE0 = MFMA32(a0, bregs[t], aE0); aE1 = MFMA32(a1, bregs[t], aE1); }
                }
                #pragma unroll
                for (int t = 2; t < 18; ++t) {
                    int ks = 2 * t;
                    int cb0 = ((ks - 4) * 32 + lk * 8) ^ xsw;
                    int cb1 = ((ks - 3) * 32 + lk * 8) ^ xsw;
                    half4 p0 = *(const half4*)(smem + lr * 2048 + cb0);
                    half4 p1 = *(const half4*)(smem + lr * 2048 + cb1);
                    half4 q0 = *(const half4*)(smem + (lr + 16) * 2048 + cb0);
                    half4 q1 = *(const half4*)(smem + (lr + 16) * 2048 + cb1);
                    half8 a0 = CAT8(p0, p1), a1 = CAT8(q0, q1);
                    if (t & 1) { aO0 = MFMA32(a0, bregs[t], aO0); aO1 = MFMA32(a1, bregs[t], aO1); }
                    else       { aE0 = MFMA32(a0, bregs[t], aE0); aE1 = MFMA32(a1, bregs[t], aE1); }
                }
                f32x4 acc0 = aE0 + aO0, acc1 = aE1 + aO1;
                float* gb = gA + w * 576;
                #pragma unroll
                for (int r = 0; r < 4; ++r) {
                    gb[(lk * 4 + r) * 18 + lr]      = acc0[r];
                    gb[(16 + lk * 4 + r) * 18 + lr] = acc1[r];
                }
            }
        } else {
            if (tt >= 1) {
                if (VAR == 1) {
                    const int q = w - 4;
                    f32x4 acc[4][2];
                    #pragma unroll
                    for (int nt = 0; nt < 4; ++nt) { acc[nt][0] = f32x4{0,0,0,0}; acc[nt][1] = f32x4{0,0,0,0}; }
                    #pragma unroll
                    for (int k2 = 0; k2 < 8; ++k2) {
                        int ks = q * 16 + k2 * 2;
                        int cb0 = (ks * 32 + lk * 8) ^ xsw;
                        int cb1 = ((ks + 1) * 32 + lk * 8) ^ xsw;
                        half4 p0 = *(const half4*)(smem + lr * 2048 + cb0);
                        half4 p1 = *(const half4*)(smem + lr * 2048 + cb1);
                        half4 q0 = *(const half4*)(smem + (lr + 16) * 2048 + cb0);
                        half4 q1 = *(const half4*)(smem + (lr + 16) * 2048 + cb1);
                        half8 a0 = CAT8(p0, p1), a1 = CAT8(q0, q1);
                        #pragma unroll
                        for (int nt = 0; nt < 4; ++nt) {
                            acc[nt][0] = MFMA32(a0, bregs[nt * 8 + k2], acc[nt][0]);
                            acc[nt][1] = MFMA32(a1, bregs[nt * 8 + k2], acc[nt][1]);
                        }
                    }
                    #pragma unroll
                    for (int nt = 0; nt < 4; ++nt)
                        #pragma unroll
                        for (int r = 0; r < 4; ++r) {
                            gB[(q * 32 + lk * 4 + r) * 66 + nt * 16 + lr]      = acc[nt][0][r];
                            gB[(q * 32 + 16 + lk * 4 + r) * 66 + nt * 16 + lr] = acc[nt][1][r];
                        }
                } else {
                    f32x4 aE0={0,0,0,0}, aO0={0,0,0,0}, aE1={0,0,0,0}, aO1={0,0,0,0};
                    #pragma unroll
                    for (int t = 0; t < 32; ++t) {
                        int ks = 2 * t;
                        int cb0 = (ks * 32 + lk * 8) ^ xsw;
                        int cb1 = ((ks + 1) * 32 + lk * 8) ^ xsw;
                        half4 p0 = *(const half4*)(smem + lr * 2048 + cb0);
                        half4 p1 = *(const half4*)(smem + lr * 2048 + cb1);
                        half4 q0 = *(const half4*)(smem + (lr + 16) * 2048 + cb0);
                        half4 q1 = *(const half4*)(smem + (lr + 16) * 2048 + cb1);
                        half8 a0 = CAT8(p0, p1), a1 = CAT8(q0, q1);
                        if (t & 1) { aO0 = MFMA32(a0, bregs[t], aO0); aO1 = MFMA32(a1, bregs[t], aO1); }
                        else       { aE0 = MFMA32(a0, bregs[t], aE0); aE1 = MFMA32(a1, bregs[t], aE1); }
                    }
                    f32x4 acc0 = aE0 + aO0, acc1 = aE1 + aO1;
                    float* gb = gB + (w - 4) * 576;
                    #pragma unroll
                    for (int r = 0; r < 4; ++r) {
                        gb[(lk * 4 + r) * 18 + lr]      = acc0[r];
                        gb[(16 + lk * 4 + r) * 18 + lr] = acc1[r];
                    }
                }
            }
        }
        __syncthreads();

        // ---- epilogue -> hbuf ----
        {
            float gv[4][2];
            if (!lay1) {
                #pragma unroll
                for (int q = 0; q < 4; ++q) {
                    f32x2 t2 = *(const f32x2*)&gA[q * 576 + er * 18 + ec];
                    gv[q][0] = t2[0]; gv[q][1] = t2[1];
                }
            } else if (VAR == 1) {
                #pragma unroll
                for (int gq = 0; gq < 4; ++gq)
                    #pragma unroll
                    for (int cc = 0; cc < 2; ++cc) {
                        float s = 0.f;
                        #pragma unroll
                        for (int qq = 0; qq < 4; ++qq)
                            s += gB[(qq * 32 + er) * 66 + gq * 16 + ec + cc];
                        gv[gq][cc] = s;
                    }
            } else {
                #pragma unroll
                for (int q = 0; q < 4; ++q) {
                    f32x2 t2 = *(const f32x2*)&gB[q * 576 + er * 18 + ec];
                    gv[q][0] = t2[0]; gv[q][1] = t2[1];
                }
            }
            half2v hv;
            #pragma unroll
            for (int cc = 0; cc < 2; ++cc) {
                float gi = gv[0][cc] + br[0][cc];
                float gf = gv[1][cc] + br[1][cc];
                float gg = gv[2][cc] + br[2][cc];
                float go = gv[3][cc] + br[3][cc];
                float cn = sigm(gf) * cstr[cc] + sigm(gi) * tanhf(gg);
                bool act = lay1 ? (tt >= 1) : (tt < T_);
                if (act) cstr[cc] = cn;
                hv[cc] = (_Float16)(sigm(go) * tanhf(cn));
            }
            *(half2v*)&hbuf[(lay1 ? 512 : 0) + er * 16 + ec] = hv;
        }
        __syncthreads();

        // ---- wave-0-only h stores + early flag ----
        if (tid < 64) {
            #pragma unroll
            for (int it = 0; it < 2; ++it) {
                int c = tid + it * 64;
                int layer = c >> 6;
                int row = (c & 63) >> 1, chunk = c & 1;
                bool act = layer ? (tt >= 1) : (tt < T_);
                if (act) {
                    f32x4 v = *(const f32x4*)&hbuf[layer * 512 + row * 16 + chunk * 8];
                    _Float16* dst = layer
                        ? (h2buf + ((tt + 1) & 1) * BH)
                        : (h1buf + (tt & 1) * BH);
                    fstore16<FAST>(&dst[(size_t)(R0 + row) * H_ + c0 + chunk * 8], v);
                }
            }
            asm volatile("s_waitcnt vmcnt(0)" ::: "memory");
            if (tt < T_ && tid == 0) fstore(myflag, (unsigned)(tt + 1));
        }
    }
}

template<int VAR>
__global__ __launch_bounds__(512, 1) void lstm_persistent(
    const float* __restrict__ x,
    const _Float16* __restrict__ Wp0, const _Float16* __restrict__ Wp1,
    const float* __restrict__ bih0, const float* __restrict__ bhh0,
    const float* __restrict__ bih1, const float* __restrict__ bhh1,
    _Float16* __restrict__ h1buf, _Float16* __restrict__ h2buf,
    unsigned* __restrict__ bar, unsigned* __restrict__ ctrl)
{
    __shared__ __attribute__((aligned(16))) char smem[110592];
    __shared__ int sinfo[3];
    const int bid = blockIdx.x;

    if (threadIdx.x == 0) {
        unsigned xcd = __builtin_amdgcn_s_getreg(20 | (7 << 11)) & 7u;
        unsigned slot = __hip_atomic_fetch_add(&ctrl[xcd], 1u,
                          __ATOMIC_RELAXED, __HIP_MEMORY_SCOPE_AGENT);
        __hip_atomic_fetch_add(&ctrl[8], 1u, __ATOMIC_RELAXED, __HIP_MEMORY_SCOPE_AGENT);
        for (int it = 0; it < 100000; ++it) {
            if (__hip_atomic_load(&ctrl[8], __ATOMIC_RELAXED, __HIP_MEMORY_SCOPE_AGENT) >= 256u)
                break;
            __builtin_amdgcn_s_sleep(8);
        }
        if (bid == 0) {
            unsigned ok = 2u;
            #pragma unroll
            for (int k = 0; k < 8; ++k)
                if (__hip_atomic_load(&ctrl[k], __ATOMIC_RELAXED, __HIP_MEMORY_SCOPE_AGENT) != 32u)
                    ok = 1u;
            __hip_atomic_store(&ctrl[9], ok, __ATOMIC_RELAXED, __HIP_MEMORY_SCOPE_AGENT);
        }
        unsigned verdict;
        while ((verdict = __hip_atomic_load(&ctrl[9], __ATOMIC_RELAXED,
                                            __HIP_MEMORY_SCOPE_AGENT)) == 0u)
            __builtin_amdgcn_s_sleep(8);
        sinfo[0] = (verdict == 2u);
        sinfo[1] = (int)xcd;
        sinfo[2] = (int)slot;
    }
    __syncthreads();

    if (sinfo[0]) {
        run_lstm<true, VAR>(sinfo[1], sinfo[2], smem, x, Wp0, Wp1,
                            bih0, bhh0, bih1, bhh1, h1buf, h2buf, bar);
    } else {
        run_lstm<false, VAR>(bid >> 5, bid & 31, smem, x, Wp0, Wp1,
                             bih0, bhh0, bih1, bhh1, h1buf, h2buf, bar);
    }
}

__global__ void fc_kernel(const _Float16* __restrict__ h2, const float* __restrict__ Wfc,
                          const float* __restrict__ bfc, float* __restrict__ out) {
    int b = blockIdx.x;
    int lidx = threadIdx.x;
    float s = 0.f;
    #pragma unroll
    for (int h = lidx; h < H_; h += 64) s += (float)h2[b * H_ + h] * Wfc[h];
    #pragma unroll
    for (int off = 32; off; off >>= 1) s += __shfl_down(s, off);
    if (lidx == 0) out[b] = s + bfc[0];
}

extern "C" void kernel_launch(void* const* d_in, const int* in_sizes, int n_in,
                              void* d_out, int out_size, void* d_ws, size_t ws_size,
                              hipStream_t stream) {
    const float* x    = (const float*)d_in[0];
    const float* Wih0 = (const float*)d_in[1];
    const float* Whh0 = (const float*)d_in[2];
    const float* bih0 = (const float*)d_in[3];
    const float* bhh0 = (const float*)d_in[4];
    const float* Wih1 = (const float*)d_in[5];
    const float* Whh1 = (const float*)d_in[6];
    const float* bih1 = (const float*)d_in[7];
    const float* bhh1 = (const float*)d_in[8];
    const float* Wfc  = (const float*)d_in[9];
    const float* bfc  = (const float*)d_in[10];
    float* out = (float*)d_out;

    char* ws = (char*)d_ws;
    unsigned*  bar   = (unsigned*)ws;                        // 64 KB flags
    unsigned*  ctrl  = (unsigned*)(ws + 65536);              // 1 KB rendezvous
    _Float16*  h1buf = (_Float16*)(ws + 66560);
    _Float16*  h2buf = (_Float16*)(ws + 66560 + 524288);
    _Float16*  Wp0   = (_Float16*)(ws + 66560 + 1048576);
    _Float16*  Wp1   = (_Float16*)(ws + 66560 + 1048576 + 2359296);

    pack_w<NKS0, I_><<<4608, 256, 0, stream>>>(Wih0, Whh0, Wp0);
    pack_w<NKS1, H_><<<8192, 256, 0, stream>>>(Wih1, Whh1, Wp1);

    // V1: layer1 K-split (candidate). V2: MALL RT probe. V0: baseline LAST (validated).
    hipMemsetAsync(d_ws, 0, 66560 + 1048576, stream);
    lstm_persistent<1><<<dim3(256), dim3(512), 0, stream>>>(
        x, Wp0, Wp1, bih0, bhh0, bih1, bhh1, h1buf, h2buf, bar, ctrl);

    hipMemsetAsync(d_ws, 0, 66560 + 1048576, stream);
    lstm_persistent<2><<<dim3(256), dim3(512), 0, stream>>>(
        x, Wp0, Wp1, bih0, bhh0, bih1, bhh1, h1buf, h2buf, bar, ctrl);

    hipMemsetAsync(d_ws, 0, 66560 + 1048576, stream);
    lstm_persistent<0><<<dim3(256), dim3(512), 0, stream>>>(
        x, Wp0, Wp1, bih0, bhh0, bih1, bhh1, h1buf, h2buf, bar, ctrl);

    fc_kernel<<<B_, 64, 0, stream>>>(h2buf + BH, Wfc, bfc, out);
}

// Round 16
// 3402.481 us; speedup vs baseline: 3.5016x; 3.5016x over previous
//
#include <hip/hip_runtime.h>
#include <hip/hip_bf16.h>

typedef __attribute__((ext_vector_type(2))) _Float16 half2v;
typedef __attribute__((ext_vector_type(4))) _Float16 half4;
typedef __attribute__((ext_vector_type(8))) _Float16 half8;
typedef __attribute__((ext_vector_type(4))) float f32x4;
typedef __attribute__((ext_vector_type(2))) float f32x2;

#define T_ 512
#define B_ 256
#define I_ 64
#define H_ 512
#define BH (B_ * H_)
#define NKS0 36
#define NKS1 64

// Wp[((cb*4+w)*NKS+ks)*256 + l*4 + i] = W[g = w*512 + cb*16 + (l&15)][k = ks*16 + (l>>4)*4 + i]
template<int NKS, int K0>
__global__ void pack_w(const float* __restrict__ Wih, const float* __restrict__ Whh,
                       _Float16* __restrict__ Wp) {
    int idx = blockIdx.x * 256 + threadIdx.x;
    int i  = idx & 3;
    int l  = (idx >> 2) & 63;
    int rest = idx >> 8;
    int ks = rest % NKS;
    int r  = rest / NKS;
    int w  = r & 3;
    int cb = r >> 2;
    int g  = w * H_ + cb * 16 + (l & 15);
    int k  = ks * 16 + ((l >> 4) << 2) + i;
    float v = (k < K0) ? Wih[(size_t)g * K0 + k] : Whh[(size_t)g * H_ + (k - K0)];
    Wp[idx] = (_Float16)v;
}

// ---- flags: ALWAYS MALL (sc0 sc1) — the only HW-validated progress path ----
__device__ __forceinline__ unsigned fload(const unsigned* p) {
    unsigned v;
    asm volatile("global_load_dword %0, %1, off sc0 sc1\n\ts_waitcnt vmcnt(0)"
                 : "=&v"(v) : "v"(p) : "memory");
    return v;
}
__device__ __forceinline__ void fstore(unsigned* p, unsigned v) {
    asm volatile("global_store_dword %0, %1, off sc0 sc1" :: "v"(p), "v"(v) : "memory");
}
template<bool FAST> __device__ __forceinline__ f32x4 gload16(const void* p) {
    f32x4 v;
    if (FAST) asm volatile("global_load_dwordx4 %0, %1, off sc0" : "=&v"(v) : "v"(p) : "memory");
    else      asm volatile("global_load_dwordx4 %0, %1, off sc0 sc1" : "=&v"(v) : "v"(p) : "memory");
    return v;
}
template<bool FAST> __device__ __forceinline__ void fstore16(void* p, f32x4 v) {
    if (FAST) asm volatile("global_store_dwordx4 %0, %1, off sc0" :: "v"(p), "v"(v) : "memory");
    else      asm volatile("global_store_dwordx4 %0, %1, off sc0 sc1" :: "v"(p), "v"(v) : "memory");
}

__device__ __forceinline__ float sigm(float z) { return 1.f / (1.f + __expf(-z)); }

#define CAT8(lo, hi) __builtin_shufflevector(lo, hi, 0, 1, 2, 3, 4, 5, 6, 7)
#define MFMA32(a, b, c) __builtin_amdgcn_mfma_f32_16x16x32_f16(a, b, c, 0, 0, 0)

// Layer0: gate-per-wave (waves 0-3). Layer1: K-SPLIT — wave q (of 4-7) owns
// K-slice [q*256, q*256+256) for ALL 4 gates; A-fragments read once from LDS and
// amortized over 8 MFMAs; fp32 partials summed via padded LDS buffer gB.
template<bool FAST>
__device__ __forceinline__ void run_lstm(
    int g, int cb, char* smem,
    const float* __restrict__ x,
    const _Float16* __restrict__ Wp0, const _Float16* __restrict__ Wp1,
    const float* __restrict__ bih0, const float* __restrict__ bhh0,
    const float* __restrict__ bih1, const float* __restrict__ bhh1,
    _Float16* __restrict__ h1buf, _Float16* __restrict__ h2buf,
    unsigned* __restrict__ bar)
{
    const int tid = threadIdx.x;
    const int w = tid >> 6, l = tid & 63;
    const int lr = l & 15, lk = l >> 4;
    const int R0 = g * 32, c0 = cb * 16;
    const int xsw = lr << 4;

    float* gA = (float*)(smem + 65536);              // [4][32][18] layer0 gates
    float* gB = (float*)(smem + 65536 + 9216);       // [4 kq][32 r][66] layer1 partials
    _Float16* hbuf = (_Float16*)(smem + 108544);     // [2][32][16]

    unsigned* grpflags = bar + (size_t)(g * 32) * 64;
    unsigned* myflag   = grpflags + (size_t)cb * 64;

    const int er = (tid >> 3) & 31;
    const int ec = (tid & 7) << 1;
    const bool lay1 = tid >= 256;

    float br[4][2];
    {
        const float* bi = lay1 ? bih1 : bih0;
        const float* bh = lay1 ? bhh1 : bhh0;
        #pragma unroll
        for (int q = 0; q < 4; ++q)
            #pragma unroll
            for (int cc = 0; cc < 2; ++cc) {
                int gc = q * H_ + c0 + ec + cc;
                br[q][cc] = bi[gc] + bh[gc];
            }
    }

    // resident weights as half8 K32-fragments (CAT8 once at init)
    half8 bregs[32];
    if (w < 4) {
        const _Float16* wb = Wp0 + ((size_t)(cb * 4 + w) * NKS0) * 256 + l * 4;
        #pragma unroll
        for (int t = 0; t < 18; ++t)
            bregs[t] = CAT8(*(const half4*)(wb + (2 * t) * 256),
                            *(const half4*)(wb + (2 * t + 1) * 256));
    } else {
        int q = w - 4;
        #pragma unroll
        for (int nt = 0; nt < 4; ++nt) {
            const _Float16* wbn = Wp1 + ((size_t)(cb * 4 + nt) * NKS1) * 256 + l * 4;
            #pragma unroll
            for (int k2 = 0; k2 < 8; ++k2) {
                int ks = q * 16 + k2 * 2;
                bregs[nt * 8 + k2] = CAT8(*(const half4*)(wbn + ks * 256),
                                          *(const half4*)(wbn + (ks + 1) * 256));
            }
        }
    }

    f32x2 cstr = {0.f, 0.f};

    for (int tt = 0; tt <= T_; ++tt) {
        f32x4 xr0[4], xr1[4];
        if (w < 4 && tt < T_) {
            const float* xa = x + (size_t)(R0 + lr) * (T_ * I_) + tt * I_ + lk * 4;
            const float* xb = x + (size_t)(R0 + 16 + lr) * (T_ * I_) + tt * I_ + lk * 4;
            #pragma unroll
            for (int ks = 0; ks < 4; ++ks) {
                xr0[ks] = *(const f32x4*)(xa + ks * 16);
                xr1[ks] = *(const f32x4*)(xb + ks * 16);
            }
        }

        // ---- poll ----
        if (tt > 0 && w == 0) {
            const unsigned tgt = (unsigned)tt;
            while (true) {
                unsigned v = fload(grpflags + (size_t)(l & 31) * 64);
                if (__all(v >= tgt)) break;
                __builtin_amdgcn_s_sleep(1);
            }
        }
        __syncthreads();

        // ---- stage tile = [ h1[tt-1] | h2[tt-2] ], swizzled g16 ^= row&15 ----
        {
            const _Float16* h1p = h1buf + ((tt + 1) & 1) * BH;
            const _Float16* h2p = h2buf + (tt & 1) * BH;
            f32x4 t[8];
            #pragma unroll
            for (int it = 0; it < 8; ++it) {
                int cch = tid + it * 512;
                int row = cch >> 7, g16 = cch & 127;
                const _Float16* src = (g16 < 64)
                    ? h1p + (size_t)(R0 + row) * H_ + (g16 << 3)
                    : h2p + (size_t)(R0 + row) * H_ + ((g16 - 64) << 3);
                t[it] = gload16<FAST>(src);
            }
            asm volatile("s_waitcnt vmcnt(0)" ::: "memory");
            __builtin_amdgcn_sched_barrier(0);
            #pragma unroll
            for (int it = 0; it < 8; ++it) {
                int cch = tid + it * 512;
                int row = cch >> 7, g16 = cch & 127;
                *(f32x4*)(smem + row * 2048 + ((g16 ^ (row & 15)) << 4)) = t[it];
            }
        }
        __syncthreads();

        // ---- MFMA ----
        if (w < 4) {
            if (tt < T_) {
                f32x4 aE0={0,0,0,0}, aO0={0,0,0,0}, aE1={0,0,0,0}, aO1={0,0,0,0};
                #pragma unroll
                for (int t = 0; t < 2; ++t) {
                    half4 lo0 = {(_Float16)xr0[2*t][0], (_Float16)xr0[2*t][1], (_Float16)xr0[2*t][2], (_Float16)xr0[2*t][3]};
                    half4 hi0 = {(_Float16)xr0[2*t+1][0], (_Float16)xr0[2*t+1][1], (_Float16)xr0[2*t+1][2], (_Float16)xr0[2*t+1][3]};
                    half4 lo1 = {(_Float16)xr1[2*t][0], (_Float16)xr1[2*t][1], (_Float16)xr1[2*t][2], (_Float16)xr1[2*t][3]};
                    half4 hi1 = {(_Float16)xr1[2*t+1][0], (_Float16)xr1[2*t+1][1], (_Float16)xr1[2*t+1][2], (_Float16)xr1[2*t+1][3]};
                    half8 a0 = CAT8(lo0, hi0), a1 = CAT8(lo1, hi1);
                    if (t & 1) { aO0 = MFMA32(a0, bregs[t], aO0); aO1 = MFMA32(a1, bregs[t], aO1); }
                    else       { aE0 = MFMA32(a0, bregs[t], aE0); aE1 = MFMA32(a1, bregs[t], aE1); }
                }
                #pragma unroll
                for (int t = 2; t < 18; ++t) {
                    int ks = 2 * t;
                    int cb0 = ((ks - 4) * 32 + lk * 8) ^ xsw;
                    int cb1 = ((ks - 3) * 32 + lk * 8) ^ xsw;
                    half4 p0 = *(const half4*)(smem + lr * 2048 + cb0);
                    half4 p1 = *(const half4*)(smem + lr * 2048 + cb1);
                    half4 q0 = *(const half4*)(smem + (lr + 16) * 2048 + cb0);
                    half4 q1 = *(const half4*)(smem + (lr + 16) * 2048 + cb1);
                    half8 a0 = CAT8(p0, p1), a1 = CAT8(q0, q1);
                    if (t & 1) { aO0 = MFMA32(a0, bregs[t], aO0); aO1 = MFMA32(a1, bregs[t], aO1); }
                    else       { aE0 = MFMA32(a0, bregs[t], aE0); aE1 = MFMA32(a1, bregs[t], aE1); }
                }
                f32x4 acc0 = aE0 + aO0, acc1 = aE1 + aO1;
                float* gb = gA + w * 576;
                #pragma unroll
                for (int r = 0; r < 4; ++r) {
                    gb[(lk * 4 + r) * 18 + lr]      = acc0[r];
                    gb[(16 + lk * 4 + r) * 18 + lr] = acc1[r];
                }
            }
        } else {
            if (tt >= 1) {
                const int q = w - 4;
                f32x4 acc[4][2];
                #pragma unroll
                for (int nt = 0; nt < 4; ++nt) { acc[nt][0] = f32x4{0,0,0,0}; acc[nt][1] = f32x4{0,0,0,0}; }
                #pragma unroll
                for (int k2 = 0; k2 < 8; ++k2) {
                    int ks = q * 16 + k2 * 2;
                    int cb0 = (ks * 32 + lk * 8) ^ xsw;
                    int cb1 = ((ks + 1) * 32 + lk * 8) ^ xsw;
                    half4 p0 = *(const half4*)(smem + lr * 2048 + cb0);
                    half4 p1 = *(const half4*)(smem + lr * 2048 + cb1);
                    half4 q0 = *(const half4*)(smem + (lr + 16) * 2048 + cb0);
                    half4 q1 = *(const half4*)(smem + (lr + 16) * 2048 + cb1);
                    half8 a0 = CAT8(p0, p1), a1 = CAT8(q0, q1);
                    #pragma unroll
                    for (int nt = 0; nt < 4; ++nt) {
                        acc[nt][0] = MFMA32(a0, bregs[nt * 8 + k2], acc[nt][0]);
                        acc[nt][1] = MFMA32(a1, bregs[nt * 8 + k2], acc[nt][1]);
                    }
                }
                #pragma unroll
                for (int nt = 0; nt < 4; ++nt)
                    #pragma unroll
                    for (int r = 0; r < 4; ++r) {
                        gB[(q * 32 + lk * 4 + r) * 66 + nt * 16 + lr]      = acc[nt][0][r];
                        gB[(q * 32 + 16 + lk * 4 + r) * 66 + nt * 16 + lr] = acc[nt][1][r];
                    }
            }
        }
        __syncthreads();

        // ---- epilogue -> hbuf ----
        {
            float gv[4][2];
            if (!lay1) {
                #pragma unroll
                for (int q = 0; q < 4; ++q) {
                    f32x2 t2 = *(const f32x2*)&gA[q * 576 + er * 18 + ec];
                    gv[q][0] = t2[0]; gv[q][1] = t2[1];
                }
            } else {
                #pragma unroll
                for (int gq = 0; gq < 4; ++gq)
                    #pragma unroll
                    for (int cc = 0; cc < 2; ++cc) {
                        float s = 0.f;
                        #pragma unroll
                        for (int qq = 0; qq < 4; ++qq)
                            s += gB[(qq * 32 + er) * 66 + gq * 16 + ec + cc];
                        gv[gq][cc] = s;
                    }
            }
            half2v hv;
            #pragma unroll
            for (int cc = 0; cc < 2; ++cc) {
                float gi = gv[0][cc] + br[0][cc];
                float gf = gv[1][cc] + br[1][cc];
                float gg = gv[2][cc] + br[2][cc];
                float go = gv[3][cc] + br[3][cc];
                float cn = sigm(gf) * cstr[cc] + sigm(gi) * tanhf(gg);
                bool act = lay1 ? (tt >= 1) : (tt < T_);
                if (act) cstr[cc] = cn;
                hv[cc] = (_Float16)(sigm(go) * tanhf(cn));
            }
            *(half2v*)&hbuf[(lay1 ? 512 : 0) + er * 16 + ec] = hv;
        }
        __syncthreads();

        // ---- wave-0-only h stores + early flag ----
        if (tid < 64) {
            #pragma unroll
            for (int it = 0; it < 2; ++it) {
                int c = tid + it * 64;
                int layer = c >> 6;
                int row = (c & 63) >> 1, chunk = c & 1;
                bool act = layer ? (tt >= 1) : (tt < T_);
                if (act) {
                    f32x4 v = *(const f32x4*)&hbuf[layer * 512 + row * 16 + chunk * 8];
                    _Float16* dst = layer
                        ? (h2buf + ((tt + 1) & 1) * BH)
                        : (h1buf + (tt & 1) * BH);
                    fstore16<FAST>(&dst[(size_t)(R0 + row) * H_ + c0 + chunk * 8], v);
                }
            }
            asm volatile("s_waitcnt vmcnt(0)" ::: "memory");
            if (tt < T_ && tid == 0) fstore(myflag, (unsigned)(tt + 1));
        }
    }
}

// ---- kernel: XCD rendezvous with SINGLE-SOURCE verdict (deadlock-free) ----
__global__ __launch_bounds__(512, 1) void lstm_persistent(
    const float* __restrict__ x,
    const _Float16* __restrict__ Wp0, const _Float16* __restrict__ Wp1,
    const float* __restrict__ bih0, const float* __restrict__ bhh0,
    const float* __restrict__ bih1, const float* __restrict__ bhh1,
    _Float16* __restrict__ h1buf, _Float16* __restrict__ h2buf,
    unsigned* __restrict__ bar, unsigned* __restrict__ ctrl)
{
    __shared__ __attribute__((aligned(16))) char smem[110592];
    __shared__ int sinfo[3];
    const int bid = blockIdx.x;

    if (threadIdx.x == 0) {
        unsigned xcd = __builtin_amdgcn_s_getreg(20 | (7 << 11)) & 7u;
        unsigned slot = __hip_atomic_fetch_add(&ctrl[xcd], 1u,
                          __ATOMIC_RELAXED, __HIP_MEMORY_SCOPE_AGENT);
        __hip_atomic_fetch_add(&ctrl[8], 1u, __ATOMIC_RELAXED, __HIP_MEMORY_SCOPE_AGENT);
        for (int it = 0; it < 100000; ++it) {
            if (__hip_atomic_load(&ctrl[8], __ATOMIC_RELAXED, __HIP_MEMORY_SCOPE_AGENT) >= 256u)
                break;
            __builtin_amdgcn_s_sleep(8);
        }
        if (bid == 0) {
            unsigned ok = 2u;
            #pragma unroll
            for (int k = 0; k < 8; ++k)
                if (__hip_atomic_load(&ctrl[k], __ATOMIC_RELAXED, __HIP_MEMORY_SCOPE_AGENT) != 32u)
                    ok = 1u;
            __hip_atomic_store(&ctrl[9], ok, __ATOMIC_RELAXED, __HIP_MEMORY_SCOPE_AGENT);
        }
        unsigned verdict;
        while ((verdict = __hip_atomic_load(&ctrl[9], __ATOMIC_RELAXED,
                                            __HIP_MEMORY_SCOPE_AGENT)) == 0u)
            __builtin_amdgcn_s_sleep(8);
        sinfo[0] = (verdict == 2u);
        sinfo[1] = (int)xcd;
        sinfo[2] = (int)slot;
    }
    __syncthreads();

    if (sinfo[0]) {
        run_lstm<true>(sinfo[1], sinfo[2], smem, x, Wp0, Wp1,
                       bih0, bhh0, bih1, bhh1, h1buf, h2buf, bar);
    } else {
        run_lstm<false>(bid >> 5, bid & 31, smem, x, Wp0, Wp1,
                        bih0, bhh0, bih1, bhh1, h1buf, h2buf, bar);
    }
}

__global__ void fc_kernel(const _Float16* __restrict__ h2, const float* __restrict__ Wfc,
                          const float* __restrict__ bfc, float* __restrict__ out) {
    int b = blockIdx.x;
    int lidx = threadIdx.x;
    float s = 0.f;
    #pragma unroll
    for (int h = lidx; h < H_; h += 64) s += (float)h2[b * H_ + h] * Wfc[h];
    #pragma unroll
    for (int off = 32; off; off >>= 1) s += __shfl_down(s, off);
    if (lidx == 0) out[b] = s + bfc[0];
}

extern "C" void kernel_launch(void* const* d_in, const int* in_sizes, int n_in,
                              void* d_out, int out_size, void* d_ws, size_t ws_size,
                              hipStream_t stream) {
    const float* x    = (const float*)d_in[0];
    const float* Wih0 = (const float*)d_in[1];
    const float* Whh0 = (const float*)d_in[2];
    const float* bih0 = (const float*)d_in[3];
    const float* bhh0 = (const float*)d_in[4];
    const float* Wih1 = (const float*)d_in[5];
    const float* Whh1 = (const float*)d_in[6];
    const float* bih1 = (const float*)d_in[7];
    const float* bhh1 = (const float*)d_in[8];
    const float* Wfc  = (const float*)d_in[9];
    const float* bfc  = (const float*)d_in[10];
    float* out = (float*)d_out;

    char* ws = (char*)d_ws;
    unsigned*  bar   = (unsigned*)ws;                        // 64 KB flags
    unsigned*  ctrl  = (unsigned*)(ws + 65536);              // 1 KB rendezvous
    _Float16*  h1buf = (_Float16*)(ws + 66560);
    _Float16*  h2buf = (_Float16*)(ws + 66560 + 524288);
    _Float16*  Wp0   = (_Float16*)(ws + 66560 + 1048576);
    _Float16*  Wp1   = (_Float16*)(ws + 66560 + 1048576 + 2359296);

    hipMemsetAsync(d_ws, 0, 66560 + 1048576, stream);
    pack_w<NKS0, I_><<<4608, 256, 0, stream>>>(Wih0, Whh0, Wp0);
    pack_w<NKS1, H_><<<8192, 256, 0, stream>>>(Wih1, Whh1, Wp1);

    lstm_persistent<<<dim3(256), dim3(512), 0, stream>>>(
        x, Wp0, Wp1, bih0, bhh0, bih1, bhh1, h1buf, h2buf, bar, ctrl);

    fc_kernel<<<B_, 64, 0, stream>>>(h2buf + BH, Wfc, bfc, out);
}

// Round 17
// 2426.857 us; speedup vs baseline: 4.9093x; 1.4020x over previous
//
#include <hip/hip_runtime.h>
#include <hip/hip_bf16.h>

typedef __attribute__((ext_vector_type(2))) _Float16 half2v;
typedef __attribute__((ext_vector_type(4))) _Float16 half4;
typedef __attribute__((ext_vector_type(8))) _Float16 half8;
typedef __attribute__((ext_vector_type(4))) float f32x4;
typedef __attribute__((ext_vector_type(2))) float f32x2;

#define T_ 512
#define B_ 256
#define I_ 64
#define H_ 512
#define BH (B_ * H_)
#define NKS0 36
#define NKS1 64

// Wp[((cb*4+w)*NKS+ks)*256 + l*4 + i] = W[g = w*512 + cb*16 + (l&15)][k = ks*16 + (l>>4)*4 + i]
template<int NKS, int K0>
__global__ void pack_w(const float* __restrict__ Wih, const float* __restrict__ Whh,
                       _Float16* __restrict__ Wp) {
    int idx = blockIdx.x * 256 + threadIdx.x;
    int i  = idx & 3;
    int l  = (idx >> 2) & 63;
    int rest = idx >> 8;
    int ks = rest % NKS;
    int r  = rest / NKS;
    int w  = r & 3;
    int cb = r >> 2;
    int g  = w * H_ + cb * 16 + (l & 15);
    int k  = ks * 16 + ((l >> 4) << 2) + i;
    float v = (k < K0) ? Wih[(size_t)g * K0 + k] : Whh[(size_t)g * H_ + (k - K0)];
    Wp[idx] = (_Float16)v;
}

// ---- flags: ALWAYS MALL (sc0 sc1) — the only HW-validated progress path ----
__device__ __forceinline__ unsigned fload(const unsigned* p) {
    unsigned v;
    asm volatile("global_load_dword %0, %1, off sc0 sc1\n\ts_waitcnt vmcnt(0)"
                 : "=&v"(v) : "v"(p) : "memory");
    return v;
}
__device__ __forceinline__ void fstore(unsigned* p, unsigned v) {
    asm volatile("global_store_dword %0, %1, off sc0 sc1" :: "v"(p), "v"(v) : "memory");
}
template<bool FAST> __device__ __forceinline__ f32x4 gload16(const void* p) {
    f32x4 v;
    if (FAST) asm volatile("global_load_dwordx4 %0, %1, off sc0" : "=&v"(v) : "v"(p) : "memory");
    else      asm volatile("global_load_dwordx4 %0, %1, off sc0 sc1" : "=&v"(v) : "v"(p) : "memory");
    return v;
}
template<bool FAST> __device__ __forceinline__ void fstore16(void* p, f32x4 v) {
    if (FAST) asm volatile("global_store_dwordx4 %0, %1, off sc0" :: "v"(p), "v"(v) : "memory");
    else      asm volatile("global_store_dwordx4 %0, %1, off sc0 sc1" :: "v"(p), "v"(v) : "memory");
}

__device__ __forceinline__ float sigm(float z) { return 1.f / (1.f + __expf(-z)); }

#define CAT8(lo, hi) __builtin_shufflevector(lo, hi, 0, 1, 2, 3, 4, 5, 6, 7)
#define MFMA32(a, b, c) __builtin_amdgcn_mfma_f32_16x16x32_f16(a, b, c, 0, 0, 0)
#define MFMA16(a, b, c) __builtin_amdgcn_mfma_f32_16x16x16f16(a, b, c, 0, 0, 0)

// BOTH layers K-split: wave q (within its layer-half) owns a K-slice for ALL 4
// gates; A-fragments read once and amortized over 8 MFMAs; fp32 partials summed
// via padded LDS buffers gA/gB (stride 66 floats, validated round 16).
// Layer0 wave q: x k-slice [16q,16q+16) (1 MFMA16/gate) + h1 k-slice [128q,+128).
// Layer1 wave q: K-slice [256q,+256) of [h1|h2].
template<bool FAST>
__device__ __forceinline__ void run_lstm(
    int g, int cb, char* smem,
    const float* __restrict__ x,
    const _Float16* __restrict__ Wp0, const _Float16* __restrict__ Wp1,
    const float* __restrict__ bih0, const float* __restrict__ bhh0,
    const float* __restrict__ bih1, const float* __restrict__ bhh1,
    _Float16* __restrict__ h1buf, _Float16* __restrict__ h2buf,
    unsigned* __restrict__ bar)
{
    const int tid = threadIdx.x;
    const int w = tid >> 6, l = tid & 63;
    const int lr = l & 15, lk = l >> 4;
    const int R0 = g * 32, c0 = cb * 16;
    const int xsw = lr << 4;

    float* gA = (float*)(smem + 65536);              // [4 kq][32 r][66] layer0 partials
    float* gB = (float*)(smem + 65536 + 33792);      // [4 kq][32 r][66] layer1 partials
    _Float16* hbuf = (_Float16*)(smem + 133120);     // [2][32][16]

    unsigned* grpflags = bar + (size_t)(g * 32) * 64;
    unsigned* myflag   = grpflags + (size_t)cb * 64;

    const int er = (tid >> 3) & 31;
    const int ec = (tid & 7) << 1;
    const bool lay1 = tid >= 256;

    float br[4][2];
    {
        const float* bi = lay1 ? bih1 : bih0;
        const float* bh = lay1 ? bhh1 : bhh0;
        #pragma unroll
        for (int q = 0; q < 4; ++q)
            #pragma unroll
            for (int cc = 0; cc < 2; ++cc) {
                int gc = q * H_ + c0 + ec + cc;
                br[q][cc] = bi[gc] + bh[gc];
            }
    }

    // resident weights (K-split both layers). layer0: bregs[nt*4+j2] (16 half8)
    // + wx[nt] (4 half4). layer1: bregs[nt*8+k2] (32 half8).
    half8 bregs[32];
    half4 wx[4];
    if (w < 4) {
        const int q = w;
        #pragma unroll
        for (int nt = 0; nt < 4; ++nt) {
            const _Float16* wbn = Wp0 + ((size_t)(cb * 4 + nt) * NKS0) * 256 + l * 4;
            wx[nt] = *(const half4*)(wbn + q * 256);
            #pragma unroll
            for (int j2 = 0; j2 < 4; ++j2) {
                int kh = 4 + 8 * q + 2 * j2;
                bregs[nt * 4 + j2] = CAT8(*(const half4*)(wbn + kh * 256),
                                          *(const half4*)(wbn + (kh + 1) * 256));
            }
        }
    } else {
        const int q = w - 4;
        #pragma unroll
        for (int nt = 0; nt < 4; ++nt) {
            const _Float16* wbn = Wp1 + ((size_t)(cb * 4 + nt) * NKS1) * 256 + l * 4;
            #pragma unroll
            for (int k2 = 0; k2 < 8; ++k2) {
                int ks = q * 16 + k2 * 2;
                bregs[nt * 8 + k2] = CAT8(*(const half4*)(wbn + ks * 256),
                                          *(const half4*)(wbn + (ks + 1) * 256));
            }
        }
    }

    f32x2 cstr = {0.f, 0.f};

    for (int tt = 0; tt <= T_; ++tt) {
        // x prefetch: layer0 wave q needs only its 16-wide k-slice (2 rows)
        f32x4 xr0, xr1;
        if (w < 4 && tt < T_) {
            const float* xa = x + (size_t)(R0 + lr) * (T_ * I_) + tt * I_ + w * 16 + lk * 4;
            const float* xb = x + (size_t)(R0 + 16 + lr) * (T_ * I_) + tt * I_ + w * 16 + lk * 4;
            xr0 = *(const f32x4*)xa;
            xr1 = *(const f32x4*)xb;
        }

        // ---- poll ----
        if (tt > 0 && w == 0) {
            const unsigned tgt = (unsigned)tt;
            while (true) {
                unsigned v = fload(grpflags + (size_t)(l & 31) * 64);
                if (__all(v >= tgt)) break;
                __builtin_amdgcn_s_sleep(1);
            }
        }
        __syncthreads();

        // ---- stage tile = [ h1[tt-1] | h2[tt-2] ], swizzled g16 ^= row&15 ----
        {
            const _Float16* h1p = h1buf + ((tt + 1) & 1) * BH;
            const _Float16* h2p = h2buf + (tt & 1) * BH;
            f32x4 t[8];
            #pragma unroll
            for (int it = 0; it < 8; ++it) {
                int cch = tid + it * 512;
                int row = cch >> 7, g16 = cch & 127;
                const _Float16* src = (g16 < 64)
                    ? h1p + (size_t)(R0 + row) * H_ + (g16 << 3)
                    : h2p + (size_t)(R0 + row) * H_ + ((g16 - 64) << 3);
                t[it] = gload16<FAST>(src);
            }
            asm volatile("s_waitcnt vmcnt(0)" ::: "memory");
            __builtin_amdgcn_sched_barrier(0);
            #pragma unroll
            for (int it = 0; it < 8; ++it) {
                int cch = tid + it * 512;
                int row = cch >> 7, g16 = cch & 127;
                *(f32x4*)(smem + row * 2048 + ((g16 ^ (row & 15)) << 4)) = t[it];
            }
        }
        __syncthreads();

        // ---- MFMA (K-split, both layers) ----
        if (w < 4) {
            if (tt < T_) {
                const int q = w;
                f32x4 acc[4][2];
                #pragma unroll
                for (int nt = 0; nt < 4; ++nt) { acc[nt][0] = f32x4{0,0,0,0}; acc[nt][1] = f32x4{0,0,0,0}; }
                // x-part: one K16 step, all 4 gates
                {
                    half4 a0 = {(_Float16)xr0[0], (_Float16)xr0[1], (_Float16)xr0[2], (_Float16)xr0[3]};
                    half4 a1 = {(_Float16)xr1[0], (_Float16)xr1[1], (_Float16)xr1[2], (_Float16)xr1[3]};
                    #pragma unroll
                    for (int nt = 0; nt < 4; ++nt) {
                        acc[nt][0] = MFMA16(a0, wx[nt], acc[nt][0]);
                        acc[nt][1] = MFMA16(a1, wx[nt], acc[nt][1]);
                    }
                }
                // h1-part: 4 K32 steps, all 4 gates
                #pragma unroll
                for (int j2 = 0; j2 < 4; ++j2) {
                    int kh = 8 * q + 2 * j2;
                    int cb0 = (kh * 32 + lk * 8) ^ xsw;
                    int cb1 = ((kh + 1) * 32 + lk * 8) ^ xsw;
                    half4 p0 = *(const half4*)(smem + lr * 2048 + cb0);
                    half4 p1 = *(const half4*)(smem + lr * 2048 + cb1);
                    half4 q0 = *(const half4*)(smem + (lr + 16) * 2048 + cb0);
                    half4 q1 = *(const half4*)(smem + (lr + 16) * 2048 + cb1);
                    half8 a0 = CAT8(p0, p1), a1 = CAT8(q0, q1);
                    #pragma unroll
                    for (int nt = 0; nt < 4; ++nt) {
                        acc[nt][0] = MFMA32(a0, bregs[nt * 4 + j2], acc[nt][0]);
                        acc[nt][1] = MFMA32(a1, bregs[nt * 4 + j2], acc[nt][1]);
                    }
                }
                #pragma unroll
                for (int nt = 0; nt < 4; ++nt)
                    #pragma unroll
                    for (int r = 0; r < 4; ++r) {
                        gA[(q * 32 + lk * 4 + r) * 66 + nt * 16 + lr]      = acc[nt][0][r];
                        gA[(q * 32 + 16 + lk * 4 + r) * 66 + nt * 16 + lr] = acc[nt][1][r];
                    }
            }
        } else {
            if (tt >= 1) {
                const int q = w - 4;
                f32x4 acc[4][2];
                #pragma unroll
                for (int nt = 0; nt < 4; ++nt) { acc[nt][0] = f32x4{0,0,0,0}; acc[nt][1] = f32x4{0,0,0,0}; }
                #pragma unroll
                for (int k2 = 0; k2 < 8; ++k2) {
                    int ks = q * 16 + k2 * 2;
                    int cb0 = (ks * 32 + lk * 8) ^ xsw;
                    int cb1 = ((ks + 1) * 32 + lk * 8) ^ xsw;
                    half4 p0 = *(const half4*)(smem + lr * 2048 + cb0);
                    half4 p1 = *(const half4*)(smem + lr * 2048 + cb1);
                    half4 q0 = *(const half4*)(smem + (lr + 16) * 2048 + cb0);
                    half4 q1 = *(const half4*)(smem + (lr + 16) * 2048 + cb1);
                    half8 a0 = CAT8(p0, p1), a1 = CAT8(q0, q1);
                    #pragma unroll
                    for (int nt = 0; nt < 4; ++nt) {
                        acc[nt][0] = MFMA32(a0, bregs[nt * 8 + k2], acc[nt][0]);
                        acc[nt][1] = MFMA32(a1, bregs[nt * 8 + k2], acc[nt][1]);
                    }
                }
                #pragma unroll
                for (int nt = 0; nt < 4; ++nt)
                    #pragma unroll
                    for (int r = 0; r < 4; ++r) {
                        gB[(q * 32 + lk * 4 + r) * 66 + nt * 16 + lr]      = acc[nt][0][r];
                        gB[(q * 32 + 16 + lk * 4 + r) * 66 + nt * 16 + lr] = acc[nt][1][r];
                    }
            }
        }
        __syncthreads();

        // ---- epilogue: sum K-partials + bias, LSTM cell -> hbuf ----
        {
            const float* gbase = lay1 ? gB : gA;
            float gv[4][2];
            #pragma unroll
            for (int gq = 0; gq < 4; ++gq)
                #pragma unroll
                for (int cc = 0; cc < 2; ++cc) {
                    float s = 0.f;
                    #pragma unroll
                    for (int qq = 0; qq < 4; ++qq)
                        s += gbase[(qq * 32 + er) * 66 + gq * 16 + ec + cc];
                    gv[gq][cc] = s;
                }
            half2v hv;
            #pragma unroll
            for (int cc = 0; cc < 2; ++cc) {
                float gi = gv[0][cc] + br[0][cc];
                float gf = gv[1][cc] + br[1][cc];
                float gg = gv[2][cc] + br[2][cc];
                float go = gv[3][cc] + br[3][cc];
                float cn = sigm(gf) * cstr[cc] + sigm(gi) * tanhf(gg);
                bool act = lay1 ? (tt >= 1) : (tt < T_);
                if (act) cstr[cc] = cn;
                hv[cc] = (_Float16)(sigm(go) * tanhf(cn));
            }
            *(half2v*)&hbuf[(lay1 ? 512 : 0) + er * 16 + ec] = hv;
        }
        __syncthreads();

        // ---- wave-0-only h stores + early flag ----
        if (tid < 64) {
            #pragma unroll
            for (int it = 0; it < 2; ++it) {
                int c = tid + it * 64;
                int layer = c >> 6;
                int row = (c & 63) >> 1, chunk = c & 1;
                bool act = layer ? (tt >= 1) : (tt < T_);
                if (act) {
                    f32x4 v = *(const f32x4*)&hbuf[layer * 512 + row * 16 + chunk * 8];
                    _Float16* dst = layer
                        ? (h2buf + ((tt + 1) & 1) * BH)
                        : (h1buf + (tt & 1) * BH);
                    fstore16<FAST>(&dst[(size_t)(R0 + row) * H_ + c0 + chunk * 8], v);
                }
            }
            asm volatile("s_waitcnt vmcnt(0)" ::: "memory");
            if (tt < T_ && tid == 0) fstore(myflag, (unsigned)(tt + 1));
        }
    }
}

// ---- kernel: XCD rendezvous with SINGLE-SOURCE verdict (deadlock-free) ----
__global__ __launch_bounds__(512, 1) void lstm_persistent(
    const float* __restrict__ x,
    const _Float16* __restrict__ Wp0, const _Float16* __restrict__ Wp1,
    const float* __restrict__ bih0, const float* __restrict__ bhh0,
    const float* __restrict__ bih1, const float* __restrict__ bhh1,
    _Float16* __restrict__ h1buf, _Float16* __restrict__ h2buf,
    unsigned* __restrict__ bar, unsigned* __restrict__ ctrl)
{
    __shared__ __attribute__((aligned(16))) char smem[135168];
    __shared__ int sinfo[3];
    const int bid = blockIdx.x;

    if (threadIdx.x == 0) {
        unsigned xcd = __builtin_amdgcn_s_getreg(20 | (7 << 11)) & 7u;
        unsigned slot = __hip_atomic_fetch_add(&ctrl[xcd], 1u,
                          __ATOMIC_RELAXED, __HIP_MEMORY_SCOPE_AGENT);
        __hip_atomic_fetch_add(&ctrl[8], 1u, __ATOMIC_RELAXED, __HIP_MEMORY_SCOPE_AGENT);
        for (int it = 0; it < 100000; ++it) {
            if (__hip_atomic_load(&ctrl[8], __ATOMIC_RELAXED, __HIP_MEMORY_SCOPE_AGENT) >= 256u)
                break;
            __builtin_amdgcn_s_sleep(8);
        }
        if (bid == 0) {
            unsigned ok = 2u;
            #pragma unroll
            for (int k = 0; k < 8; ++k)
                if (__hip_atomic_load(&ctrl[k], __ATOMIC_RELAXED, __HIP_MEMORY_SCOPE_AGENT) != 32u)
                    ok = 1u;
            __hip_atomic_store(&ctrl[9], ok, __ATOMIC_RELAXED, __HIP_MEMORY_SCOPE_AGENT);
        }
        unsigned verdict;
        while ((verdict = __hip_atomic_load(&ctrl[9], __ATOMIC_RELAXED,
                                            __HIP_MEMORY_SCOPE_AGENT)) == 0u)
            __builtin_amdgcn_s_sleep(8);
        sinfo[0] = (verdict == 2u);
        sinfo[1] = (int)xcd;
        sinfo[2] = (int)slot;
    }
    __syncthreads();

    if (sinfo[0]) {
        run_lstm<true>(sinfo[1], sinfo[2], smem, x, Wp0, Wp1,
                       bih0, bhh0, bih1, bhh1, h1buf, h2buf, bar);
    } else {
        run_lstm<false>(bid >> 5, bid & 31, smem, x, Wp0, Wp1,
                        bih0, bhh0, bih1, bhh1, h1buf, h2buf, bar);
    }
}

__global__ void fc_kernel(const _Float16* __restrict__ h2, const float* __restrict__ Wfc,
                          const float* __restrict__ bfc, float* __restrict__ out) {
    int b = blockIdx.x;
    int lidx = threadIdx.x;
    float s = 0.f;
    #pragma unroll
    for (int h = lidx; h < H_; h += 64) s += (float)h2[b * H_ + h] * Wfc[h];
    #pragma unroll
    for (int off = 32; off; off >>= 1) s += __shfl_down(s, off);
    if (lidx == 0) out[b] = s + bfc[0];
}

extern "C" void kernel_launch(void* const* d_in, const int* in_sizes, int n_in,
                              void* d_out, int out_size, void* d_ws, size_t ws_size,
                              hipStream_t stream) {
    const float* x    = (const float*)d_in[0];
    const float* Wih0 = (const float*)d_in[1];
    const float* Whh0 = (const float*)d_in[2];
    const float* bih0 = (const float*)d_in[3];
    const float* bhh0 = (const float*)d_in[4];
    const float* Wih1 = (const float*)d_in[5];
    const float* Whh1 = (const float*)d_in[6];
    const float* bih1 = (const float*)d_in[7];
    const float* bhh1 = (const float*)d_in[8];
    const float* Wfc  = (const float*)d_in[9];
    const float* bfc  = (const float*)d_in[10];
    float* out = (float*)d_out;

    char* ws = (char*)d_ws;
    unsigned*  bar   = (unsigned*)ws;                        // 64 KB flags
    unsigned*  ctrl  = (unsigned*)(ws + 65536);              // 1 KB rendezvous
    _Float16*  h1buf = (_Float16*)(ws + 66560);
    _Float16*  h2buf = (_Float16*)(ws + 66560 + 524288);
    _Float16*  Wp0   = (_Float16*)(ws + 66560 + 1048576);
    _Float16*  Wp1   = (_Float16*)(ws + 66560 + 1048576 + 2359296);

    hipMemsetAsync(d_ws, 0, 66560 + 1048576, stream);
    pack_w<NKS0, I_><<<4608, 256, 0, stream>>>(Wih0, Whh0, Wp0);
    pack_w<NKS1, H_><<<8192, 256, 0, stream>>>(Wih1, Whh1, Wp1);

    lstm_persistent<<<dim3(256), dim3(512), 0, stream>>>(
        x, Wp0, Wp1, bih0, bhh0, bih1, bhh1, h1buf, h2buf, bar, ctrl);

    fc_kernel<<<B_, 64, 0, stream>>>(h2buf + BH, Wfc, bfc, out);
}